// Round 1
// baseline (321.916 us; speedup 1.0000x reference)
//
#include <hip/hip_runtime.h>
#include <math.h>

// Problem dims (fixed by setup_inputs)
constexpr int Bc = 64;
constexpr int Tc = 1000;
constexpr int Vc = 512;
constexpr int Uc = 256;
constexpr int CH = 50;        // t-rows per LDS chunk (scan)
constexpr int NCH = Tc / CH;  // 20 chunks
constexpr int PW = 7;         // fused fallback: producer waves
constexpr int SLOTS = 4;      // fused fallback: stage slots per producer wave

// gather kernel geometry
constexpr int GW = 4;               // waves per gather block
constexpr int GSL = 5;              // stage slots per wave
constexpr int GROWS = GW * GSL * 2; // 40 rows per gather block
constexpr int GBLK = Tc / GROWS;    // 25 gather blocks per batch elem

#define NEG_INF_F (-100000.0f)
#define LOG2E_F 1.44269504088896340736f
#define LN2_F 0.69314718055994530942f
#define DEAD_F (-1.0e9f)

// raw v_exp_f32 (2^x) / v_log_f32 (log2 x)
__device__ __forceinline__ float fexp2(float x) {
#if __has_builtin(__builtin_amdgcn_exp2f)
    return __builtin_amdgcn_exp2f(x);
#else
    return __expf(x * LN2_F);
#endif
}
__device__ __forceinline__ float flog2(float x) {
#if __has_builtin(__builtin_amdgcn_logf)
    return __builtin_amdgcn_logf(x);
#else
    return __logf(x) * LOG2E_F;
#endif
}

// log2-domain logadd: log2(2^x + 2^y)
__device__ __forceinline__ float l2add(float x, float y) {
    float m = fmaxf(x, y);
    float p = fexp2(-fabsf(x - y));
    return m + flog2(1.0f + p);
}

// One HMM step in shifted log2 domain (transition consts folded into E2).
__device__ __forceinline__ void hmm_step(float rr[4], const float4 ev, float pen) {
    float nb0 = __shfl_up(rr[3], 1, 64) + pen; // lane0: own value - 1e9 ~= -inf
    float e[4] = {ev.x, ev.y, ev.z, ev.w};
    float nb[4] = {nb0, rr[0], rr[1], rr[2]};
#pragma unroll
    for (int c = 0; c < 4; ++c) {
        float x = rr[c], y = nb[c];
        float m = fmaxf(x, y);
        float p = fexp2(-fabsf(x - y));
        rr[c] = m + flog2(1.0f + p) + e[c];
    }
}

// async global->LDS DMA of 16 B/lane (1 KB per wave-instruction)
__device__ __forceinline__ void dma16(const float* gsrc, float* lds, int lane) {
    typedef const __attribute__((address_space(1))) unsigned int* gp_t;
    typedef __attribute__((address_space(3))) unsigned int* lp_t;
    __builtin_amdgcn_global_load_lds((gp_t)(const void*)(gsrc + 4 * lane),
                                     (lp_t)(void*)lds, 16, 0, 0);
}

// ---------------------------------------------------------------------------
// Kernel A: gather + transform emissions to E2[b][t][u] (all 256 CUs busy).
// E2 form: ev = lp[b,t,phns[u]]*log2(e) + off(u), masked by (u<Uv)&(t<Tv).
// ---------------------------------------------------------------------------
__global__ __launch_bounds__(256, 4) void gather_kernel(
    const float* __restrict__ lp, const float* __restrict__ lens,
    const int* __restrict__ phns, const float* __restrict__ phn_lens,
    float* __restrict__ e2) {
    __shared__ float stage[GW][GSL][Vc]; // 40 KB -> 4 blocks/CU
    const int b = blockIdx.x;
    const int t0 = blockIdx.y * GROWS;
    const int tid = threadIdx.x;
    const int wave = tid >> 6;
    const int lane = tid & 63;
    const int Tv = (int)rintf(lens[b] * (float)Tc);
    const int Uv = (int)rintf(phn_lens[b] * (float)Uc);
    const float* lpb = lp + (size_t)b * Tc * Vc;
    float* e2b = e2 + ((size_t)b * Tc + t0) * Uc;

    int col[4];
    float off[4];
    bool pv[4];
    int4 cc = *(const int4*)(phns + (size_t)b * Uc + 4 * lane);
    int c4[4] = {cc.x, cc.y, cc.z, cc.w};
#pragma unroll
    for (int c = 0; c < 4; ++c) {
        int v = c4[c];
        v = v < 0 ? 0 : (v > Vc - 1 ? Vc - 1 : v);
        col[c] = v;
        int i = 4 * lane + c;
        pv[c] = (i < Uv);
        off[c] = (i == Uv - 1) ? 0.0f : -1.0f; // transition const (log2 units)
    }

    float* stw = &stage[wave][0][0];
#pragma unroll
    for (int half = 0; half < 2; ++half) {
#pragma unroll
        for (int j = 0; j < GSL; ++j) {
            int r = wave + (half * GSL + j) * GW;
            const float* gsrc = lpb + (size_t)(t0 + r) * Vc;
            float* st = stw + j * Vc;
            dma16(gsrc, st, lane);             // floats [0..255]
            dma16(gsrc + 256, st + 256, lane); // floats [256..511]
        }
        __builtin_amdgcn_s_waitcnt(0x0f70); // vmcnt(0), ignore exp/lgkm
#pragma unroll
        for (int j = 0; j < GSL; ++j) {
            int r = wave + (half * GSL + j) * GW;
            const bool tv = (t0 + r) < Tv;
            const float* st = stw + j * Vc;
            float ev[4];
#pragma unroll
            for (int c = 0; c < 4; ++c) {
                float e = st[col[c]]; // random-bank ds_read_b32
                ev[c] = (pv[c] && tv) ? fmaf(e, LOG2E_F, off[c])
                                      : (NEG_INF_F * LOG2E_F + off[c]);
            }
            *(float4*)(e2b + (size_t)r * Uc + 4 * lane) =
                make_float4(ev[0], ev[1], ev[2], ev[3]);
        }
    }
}

// ---------------------------------------------------------------------------
// Kernel B: sequential scan over precomputed E2. 1 consumer + 1 DMA wave.
// Producer has zero drain work (E2 rows are contiguous 1 KB DMAs).
// ---------------------------------------------------------------------------
__global__ __launch_bounds__(128, 1) void scan_kernel(
    const float* __restrict__ e2, const float* __restrict__ phn_lens,
    float* __restrict__ out) {
    __shared__ float ebuf[2][CH][Uc]; // 100 KB double buffer
    const int b = blockIdx.x;
    const int tid = threadIdx.x;
    const int wave = tid >> 6;
    const int lane = tid & 63;
    const int Uv = (int)rintf(phn_lens[b] * (float)Uc);
    const float* eb = e2 + (size_t)b * Tc * Uc;
    float rr[4];
    const float pen = (lane == 0) ? DEAD_F : 0.0f;

    auto fill = [&](int k) {
        const float* src = eb + (size_t)k * CH * Uc;
        float* dst = &ebuf[k & 1][0][0];
#pragma unroll 5
        for (int r = 0; r < CH; ++r)
            dma16(src + (size_t)r * Uc, dst + r * Uc, lane); // 1 row = 1 KB
    };

    auto consume = [&](int k) {
        const float4* base = (const float4*)&ebuf[k & 1][0][0] + lane;
        int r = 0;
        if (k == 0) {
            float4 e0 = base[0];
            float ea[4] = {e0.x, e0.y, e0.z, e0.w};
#pragma unroll
            for (int c = 0; c < 4; ++c)
                rr[c] = ((4 * lane + c == 0) ? 0.0f : DEAD_F) + ea[c]; // pi + E2(0)
            r = 1;
        }
        float4 q0, q1, q2, q3;
        if (r + 0 < CH) q0 = base[(r + 0) * 64];
        if (r + 1 < CH) q1 = base[(r + 1) * 64];
        if (r + 2 < CH) q2 = base[(r + 2) * 64];
        if (r + 3 < CH) q3 = base[(r + 3) * 64];
        while (r + 4 <= CH) {
            float4 e0 = q0, e1 = q1, e2v = q2, e3 = q3;
            if (r + 4 < CH) q0 = base[(r + 4) * 64];
            if (r + 5 < CH) q1 = base[(r + 5) * 64];
            if (r + 6 < CH) q2 = base[(r + 6) * 64];
            if (r + 7 < CH) q3 = base[(r + 7) * 64];
            hmm_step(rr, e0, pen);
            hmm_step(rr, e1, pen);
            hmm_step(rr, e2v, pen);
            hmm_step(rr, e3, pen);
            r += 4;
        }
        if (r + 0 < CH) hmm_step(rr, q0, pen);
        if (r + 1 < CH) hmm_step(rr, q1, pen);
        if (r + 2 < CH) hmm_step(rr, q2, pen);
    };

    if (wave == 1) fill(0);
    __syncthreads();
    for (int k = 0; k < NCH; ++k) {
        if (wave == 1) {
            if (k + 1 < NCH) fill(k + 1);
        } else {
            consume(k);
        }
        __syncthreads();
    }

    if (wave == 0) {
        float a[4];
#pragma unroll
        for (int c = 0; c < 4; ++c)
            a[c] = rr[c] + ((4 * lane + c == Uv - 1) ? 0.0f : 1.0f);
        float r2 = l2add(l2add(a[0], a[1]), l2add(a[2], a[3]));
#pragma unroll
        for (int o = 32; o >= 1; o >>= 1) {
            float t = __shfl_xor(r2, o, 64);
            r2 = l2add(r2, t);
        }
        if (lane == 0) out[b] = r2 * LN2_F; // back to nats
    }
}

// ---------------------------------------------------------------------------
// Fallback: previous fused single-kernel version (used if workspace too small)
// ---------------------------------------------------------------------------
__global__ __launch_bounds__(512, 1) void fused_hmm_kernel(
    const float* __restrict__ lp, const float* __restrict__ lens,
    const int* __restrict__ phns, const float* __restrict__ phn_lens,
    float* __restrict__ out) {
    __shared__ float ebuf[2][CH][Uc];      // 100 KB
    __shared__ float stage[PW][SLOTS][Vc]; // 56 KB
    const int b = blockIdx.x;
    const int tid = threadIdx.x;
    const int wave = tid >> 6;
    const int lane = tid & 63;
    const int Tv = (int)rintf(lens[b] * (float)Tc);
    const int Uv = (int)rintf(phn_lens[b] * (float)Uc);
    const float* lpb = lp + (size_t)b * Tc * Vc;

    int col[4];
    float off[4];
    bool pv[4];
    float rr[4];
    const float pen = (lane == 0) ? DEAD_F : 0.0f;

    if (wave > 0) {
        int4 cc = *(const int4*)(phns + (size_t)b * Uc + 4 * lane);
        int c4[4] = {cc.x, cc.y, cc.z, cc.w};
#pragma unroll
        for (int c = 0; c < 4; ++c) {
            int v = c4[c];
            v = v < 0 ? 0 : (v > Vc - 1 ? Vc - 1 : v);
            col[c] = v;
            int i = 4 * lane + c;
            pv[c] = (i < Uv);
            off[c] = (i == Uv - 1) ? 0.0f : -1.0f;
        }
    }

    auto fill = [&](int k) {
        float* dst = &ebuf[k & 1][0][0];
        const int tb = k * CH;
        const int r0 = wave - 1;
        float* stw = &stage[wave - 1][0][0];
#pragma unroll
        for (int half = 0; half < 2; ++half) {
#pragma unroll
            for (int jj = 0; jj < SLOTS; ++jj) {
                int r = r0 + (half * SLOTS + jj) * PW;
                if (r < CH) {
                    const float* gsrc = lpb + (size_t)(tb + r) * Vc;
                    float* st = stw + jj * Vc;
                    dma16(gsrc, st, lane);
                    dma16(gsrc + 256, st + 256, lane);
                }
            }
            __builtin_amdgcn_s_waitcnt(0x0f70);
#pragma unroll
            for (int jj = 0; jj < SLOTS; ++jj) {
                int r = r0 + (half * SLOTS + jj) * PW;
                if (r < CH) {
                    const bool tv = (tb + r) < Tv;
                    const float* st = stw + jj * Vc;
                    float ev[4];
#pragma unroll
                    for (int c = 0; c < 4; ++c) {
                        float e = st[col[c]];
                        ev[c] = (pv[c] && tv) ? fmaf(e, LOG2E_F, off[c])
                                              : (NEG_INF_F * LOG2E_F + off[c]);
                    }
                    *(float4*)(dst + r * Uc + 4 * lane) =
                        make_float4(ev[0], ev[1], ev[2], ev[3]);
                }
            }
        }
    };

    auto consume = [&](int k) {
        const float4* base = (const float4*)&ebuf[k & 1][0][0] + lane;
        int r = 0;
        if (k == 0) {
            float4 e0 = base[0];
            float ea[4] = {e0.x, e0.y, e0.z, e0.w};
#pragma unroll
            for (int c = 0; c < 4; ++c)
                rr[c] = ((4 * lane + c == 0) ? 0.0f : DEAD_F) + ea[c];
            r = 1;
        }
        float4 q0, q1, q2, q3;
        if (r + 0 < CH) q0 = base[(r + 0) * 64];
        if (r + 1 < CH) q1 = base[(r + 1) * 64];
        if (r + 2 < CH) q2 = base[(r + 2) * 64];
        if (r + 3 < CH) q3 = base[(r + 3) * 64];
        while (r + 4 <= CH) {
            float4 e0 = q0, e1 = q1, e2 = q2, e3 = q3;
            if (r + 4 < CH) q0 = base[(r + 4) * 64];
            if (r + 5 < CH) q1 = base[(r + 5) * 64];
            if (r + 6 < CH) q2 = base[(r + 6) * 64];
            if (r + 7 < CH) q3 = base[(r + 7) * 64];
            hmm_step(rr, e0, pen);
            hmm_step(rr, e1, pen);
            hmm_step(rr, e2, pen);
            hmm_step(rr, e3, pen);
            r += 4;
        }
        if (r + 0 < CH) hmm_step(rr, q0, pen);
        if (r + 1 < CH) hmm_step(rr, q1, pen);
        if (r + 2 < CH) hmm_step(rr, q2, pen);
    };

    if (wave > 0) fill(0);
    __syncthreads();
    for (int k = 0; k < NCH; ++k) {
        if (wave > 0) {
            if (k + 1 < NCH) fill(k + 1);
        } else {
            consume(k);
        }
        __syncthreads();
    }

    if (wave == 0) {
        float a[4];
#pragma unroll
        for (int c = 0; c < 4; ++c)
            a[c] = rr[c] + ((4 * lane + c == Uv - 1) ? 0.0f : 1.0f);
        float r2 = l2add(l2add(a[0], a[1]), l2add(a[2], a[3]));
#pragma unroll
        for (int o = 32; o >= 1; o >>= 1) {
            float t = __shfl_xor(r2, o, 64);
            r2 = l2add(r2, t);
        }
        if (lane == 0) out[b] = r2 * LN2_F;
    }
}

extern "C" void kernel_launch(void* const* d_in, const int* in_sizes, int n_in,
                              void* d_out, int out_size, void* d_ws, size_t ws_size,
                              hipStream_t stream) {
    const float* lp = (const float*)d_in[0];
    const float* lens = (const float*)d_in[1];
    const int* phns = (const int*)d_in[2];
    const float* phn_lens = (const float*)d_in[3];
    float* out = (float*)d_out;
    (void)in_sizes; (void)n_in; (void)out_size;

    const size_t need = (size_t)Bc * Tc * Uc * sizeof(float); // 65.5 MB
    if (d_ws != nullptr && ws_size >= need) {
        float* e2 = (float*)d_ws;
        gather_kernel<<<dim3(Bc, GBLK), 256, 0, stream>>>(lp, lens, phns,
                                                          phn_lens, e2);
        scan_kernel<<<Bc, 128, 0, stream>>>(e2, phn_lens, out);
    } else {
        fused_hmm_kernel<<<Bc, 512, 0, stream>>>(lp, lens, phns, phn_lens, out);
    }
}

// Round 2
// 289.677 us; speedup vs baseline: 1.1113x; 1.1113x over previous
//
#include <hip/hip_runtime.h>
#include <math.h>

// Problem dims (fixed by setup_inputs)
constexpr int Bc = 64;
constexpr int Tc = 1000;
constexpr int Vc = 512;
constexpr int Uc = 256;
constexpr int CH = 50;        // t-rows per LDS chunk (scan)
constexpr int NCH = Tc / CH;  // 20 chunks
constexpr int PW = 7;         // fused fallback: producer waves
constexpr int SLOTS = 4;      // fused fallback: stage slots per producer wave

// gather kernel geometry
constexpr int GW = 4;               // waves per gather block
constexpr int GSL = 5;              // stage slots per wave
constexpr int GROWS = GW * GSL * 2; // 40 rows per gather block
constexpr int GBLK = Tc / GROWS;    // 25 gather blocks per batch elem

#define NEG_INF_F (-100000.0f)
#define LOG2E_F 1.44269504088896340736f
#define LN2_F 0.69314718055994530942f
#define DEAD_F (-1.0e9f)

// raw v_exp_f32 (2^x) / v_log_f32 (log2 x)
__device__ __forceinline__ float fexp2(float x) {
#if __has_builtin(__builtin_amdgcn_exp2f)
    return __builtin_amdgcn_exp2f(x);
#else
    return __expf(x * LN2_F);
#endif
}
__device__ __forceinline__ float flog2(float x) {
#if __has_builtin(__builtin_amdgcn_logf)
    return __builtin_amdgcn_logf(x);
#else
    return __logf(x) * LOG2E_F;
#endif
}

// log2-domain logadd: log2(2^x + 2^y)
__device__ __forceinline__ float l2add(float x, float y) {
    float m = fmaxf(x, y);
    float p = fexp2(-fabsf(x - y));
    return m + flog2(1.0f + p);
}

// Whole-wave shift-up-by-1 via DPP wave_shr:1 (gfx9-family VALU op, ~8 cyc —
// replaces ds_permute + lgkmcnt(0) ~120+ cyc on the per-step critical path).
// Lane n gets lane n-1's x; lane 0 gets `lane0val` (bound_ctrl=false -> old).
__device__ __forceinline__ float waveshr1(float x, float lane0val) {
    return __int_as_float(__builtin_amdgcn_update_dpp(
        __float_as_int(lane0val), __float_as_int(x),
        0x138 /* wave_shr:1 */, 0xF, 0xF, false));
}

// One HMM step in shifted log2 domain (transition consts folded into E2):
//   r_i(t) = log2add(r_i(t-1), r_{i-1}(t-1)) + E2_i(t)
// Lane holds states i = 4*lane + c; only c=0 crosses lanes (DPP, cheap).
// Reassociated as (m + e) + log2(1+p): the m+e add runs parallel to the
// exp2->log2 transcendental chain.
__device__ __forceinline__ void hmm_step(float rr[4], const float4 ev) {
    float nb0 = waveshr1(rr[3], DEAD_F); // lane0: -1e9 ~= -inf
    float e[4] = {ev.x, ev.y, ev.z, ev.w};
    float nb[4] = {nb0, rr[0], rr[1], rr[2]};
#pragma unroll
    for (int c = 0; c < 4; ++c) {
        float x = rr[c], y = nb[c];
        float m = fmaxf(x, y);
        float p = fexp2(-fabsf(x - y));
        float me = m + e[c];
        rr[c] = me + flog2(1.0f + p);
    }
}

// async global->LDS DMA of 16 B/lane (1 KB per wave-instruction)
__device__ __forceinline__ void dma16(const float* gsrc, float* lds, int lane) {
    typedef const __attribute__((address_space(1))) unsigned int* gp_t;
    typedef __attribute__((address_space(3))) unsigned int* lp_t;
    __builtin_amdgcn_global_load_lds((gp_t)(const void*)(gsrc + 4 * lane),
                                     (lp_t)(void*)lds, 16, 0, 0);
}

// ---------------------------------------------------------------------------
// Kernel A: gather + transform emissions to E2[b][t][u] (all 256 CUs busy).
// E2 form: ev = lp[b,t,phns[u]]*log2(e) + off(u), masked by (u<Uv)&(t<Tv).
// ---------------------------------------------------------------------------
__global__ __launch_bounds__(256, 4) void gather_kernel(
    const float* __restrict__ lp, const float* __restrict__ lens,
    const int* __restrict__ phns, const float* __restrict__ phn_lens,
    float* __restrict__ e2) {
    __shared__ float stage[GW][GSL][Vc]; // 40 KB -> 4 blocks/CU
    const int b = blockIdx.x;
    const int t0 = blockIdx.y * GROWS;
    const int tid = threadIdx.x;
    const int wave = tid >> 6;
    const int lane = tid & 63;
    const int Tv = (int)rintf(lens[b] * (float)Tc);
    const int Uv = (int)rintf(phn_lens[b] * (float)Uc);
    const float* lpb = lp + (size_t)b * Tc * Vc;
    float* e2b = e2 + ((size_t)b * Tc + t0) * Uc;

    int col[4];
    float off[4];
    bool pv[4];
    int4 cc = *(const int4*)(phns + (size_t)b * Uc + 4 * lane);
    int c4[4] = {cc.x, cc.y, cc.z, cc.w};
#pragma unroll
    for (int c = 0; c < 4; ++c) {
        int v = c4[c];
        v = v < 0 ? 0 : (v > Vc - 1 ? Vc - 1 : v);
        col[c] = v;
        int i = 4 * lane + c;
        pv[c] = (i < Uv);
        off[c] = (i == Uv - 1) ? 0.0f : -1.0f; // transition const (log2 units)
    }

    float* stw = &stage[wave][0][0];
#pragma unroll
    for (int half = 0; half < 2; ++half) {
#pragma unroll
        for (int j = 0; j < GSL; ++j) {
            int r = wave + (half * GSL + j) * GW;
            const float* gsrc = lpb + (size_t)(t0 + r) * Vc;
            float* st = stw + j * Vc;
            dma16(gsrc, st, lane);             // floats [0..255]
            dma16(gsrc + 256, st + 256, lane); // floats [256..511]
        }
        __builtin_amdgcn_s_waitcnt(0x0f70); // vmcnt(0), ignore exp/lgkm
#pragma unroll
        for (int j = 0; j < GSL; ++j) {
            int r = wave + (half * GSL + j) * GW;
            const bool tv = (t0 + r) < Tv;
            const float* st = stw + j * Vc;
            float ev[4];
#pragma unroll
            for (int c = 0; c < 4; ++c) {
                float e = st[col[c]]; // random-bank ds_read_b32
                ev[c] = (pv[c] && tv) ? fmaf(e, LOG2E_F, off[c])
                                      : (NEG_INF_F * LOG2E_F + off[c]);
            }
            *(float4*)(e2b + (size_t)r * Uc + 4 * lane) =
                make_float4(ev[0], ev[1], ev[2], ev[3]);
        }
    }
}

// ---------------------------------------------------------------------------
// Kernel B: sequential scan over precomputed E2. 1 consumer + 1 DMA wave.
// ---------------------------------------------------------------------------
__global__ __launch_bounds__(128, 1) void scan_kernel(
    const float* __restrict__ e2, const float* __restrict__ phn_lens,
    float* __restrict__ out) {
    __shared__ float ebuf[2][CH][Uc]; // 100 KB double buffer
    const int b = blockIdx.x;
    const int tid = threadIdx.x;
    const int wave = tid >> 6;
    const int lane = tid & 63;
    const int Uv = (int)rintf(phn_lens[b] * (float)Uc);
    const float* eb = e2 + (size_t)b * Tc * Uc;
    float rr[4];

    auto fill = [&](int k) {
        const float* src = eb + (size_t)k * CH * Uc;
        float* dst = &ebuf[k & 1][0][0];
#pragma unroll 5
        for (int r = 0; r < CH; ++r)
            dma16(src + (size_t)r * Uc, dst + r * Uc, lane); // 1 row = 1 KB
    };

    auto consume = [&](int k) {
        const float4* base = (const float4*)&ebuf[k & 1][0][0] + lane;
        int r = 0;
        if (k == 0) {
            float4 e0 = base[0];
            float ea[4] = {e0.x, e0.y, e0.z, e0.w};
#pragma unroll
            for (int c = 0; c < 4; ++c)
                rr[c] = ((4 * lane + c == 0) ? 0.0f : DEAD_F) + ea[c]; // pi + E2(0)
            r = 1;
        }
        float4 q0, q1, q2, q3;
        if (r + 0 < CH) q0 = base[(r + 0) * 64];
        if (r + 1 < CH) q1 = base[(r + 1) * 64];
        if (r + 2 < CH) q2 = base[(r + 2) * 64];
        if (r + 3 < CH) q3 = base[(r + 3) * 64];
        while (r + 4 <= CH) {
            float4 e0 = q0, e1 = q1, e2v = q2, e3 = q3;
            if (r + 4 < CH) q0 = base[(r + 4) * 64];
            if (r + 5 < CH) q1 = base[(r + 5) * 64];
            if (r + 6 < CH) q2 = base[(r + 6) * 64];
            if (r + 7 < CH) q3 = base[(r + 7) * 64];
            hmm_step(rr, e0);
            hmm_step(rr, e1);
            hmm_step(rr, e2v);
            hmm_step(rr, e3);
            r += 4;
        }
        if (r + 0 < CH) hmm_step(rr, q0);
        if (r + 1 < CH) hmm_step(rr, q1);
        if (r + 2 < CH) hmm_step(rr, q2);
    };

    if (wave == 1) fill(0);
    __syncthreads();
    for (int k = 0; k < NCH; ++k) {
        if (wave == 1) {
            if (k + 1 < NCH) fill(k + 1);
        } else {
            consume(k);
        }
        __syncthreads();
    }

    if (wave == 0) {
        float a[4];
#pragma unroll
        for (int c = 0; c < 4; ++c)
            a[c] = rr[c] + ((4 * lane + c == Uv - 1) ? 0.0f : 1.0f);
        float r2 = l2add(l2add(a[0], a[1]), l2add(a[2], a[3]));
#pragma unroll
        for (int o = 32; o >= 1; o >>= 1) {
            float t = __shfl_xor(r2, o, 64);
            r2 = l2add(r2, t);
        }
        if (lane == 0) out[b] = r2 * LN2_F; // back to nats
    }
}

// ---------------------------------------------------------------------------
// Fallback: fused single-kernel version (used if workspace too small)
// ---------------------------------------------------------------------------
__global__ __launch_bounds__(512, 1) void fused_hmm_kernel(
    const float* __restrict__ lp, const float* __restrict__ lens,
    const int* __restrict__ phns, const float* __restrict__ phn_lens,
    float* __restrict__ out) {
    __shared__ float ebuf[2][CH][Uc];      // 100 KB
    __shared__ float stage[PW][SLOTS][Vc]; // 56 KB
    const int b = blockIdx.x;
    const int tid = threadIdx.x;
    const int wave = tid >> 6;
    const int lane = tid & 63;
    const int Tv = (int)rintf(lens[b] * (float)Tc);
    const int Uv = (int)rintf(phn_lens[b] * (float)Uc);
    const float* lpb = lp + (size_t)b * Tc * Vc;

    int col[4];
    float off[4];
    bool pv[4];
    float rr[4];

    if (wave > 0) {
        int4 cc = *(const int4*)(phns + (size_t)b * Uc + 4 * lane);
        int c4[4] = {cc.x, cc.y, cc.z, cc.w};
#pragma unroll
        for (int c = 0; c < 4; ++c) {
            int v = c4[c];
            v = v < 0 ? 0 : (v > Vc - 1 ? Vc - 1 : v);
            col[c] = v;
            int i = 4 * lane + c;
            pv[c] = (i < Uv);
            off[c] = (i == Uv - 1) ? 0.0f : -1.0f;
        }
    }

    auto fill = [&](int k) {
        float* dst = &ebuf[k & 1][0][0];
        const int tb = k * CH;
        const int r0 = wave - 1;
        float* stw = &stage[wave - 1][0][0];
#pragma unroll
        for (int half = 0; half < 2; ++half) {
#pragma unroll
            for (int jj = 0; jj < SLOTS; ++jj) {
                int r = r0 + (half * SLOTS + jj) * PW;
                if (r < CH) {
                    const float* gsrc = lpb + (size_t)(tb + r) * Vc;
                    float* st = stw + jj * Vc;
                    dma16(gsrc, st, lane);
                    dma16(gsrc + 256, st + 256, lane);
                }
            }
            __builtin_amdgcn_s_waitcnt(0x0f70);
#pragma unroll
            for (int jj = 0; jj < SLOTS; ++jj) {
                int r = r0 + (half * SLOTS + jj) * PW;
                if (r < CH) {
                    const bool tv = (tb + r) < Tv;
                    const float* st = stw + jj * Vc;
                    float ev[4];
#pragma unroll
                    for (int c = 0; c < 4; ++c) {
                        float e = st[col[c]];
                        ev[c] = (pv[c] && tv) ? fmaf(e, LOG2E_F, off[c])
                                              : (NEG_INF_F * LOG2E_F + off[c]);
                    }
                    *(float4*)(dst + r * Uc + 4 * lane) =
                        make_float4(ev[0], ev[1], ev[2], ev[3]);
                }
            }
        }
    };

    auto consume = [&](int k) {
        const float4* base = (const float4*)&ebuf[k & 1][0][0] + lane;
        int r = 0;
        if (k == 0) {
            float4 e0 = base[0];
            float ea[4] = {e0.x, e0.y, e0.z, e0.w};
#pragma unroll
            for (int c = 0; c < 4; ++c)
                rr[c] = ((4 * lane + c == 0) ? 0.0f : DEAD_F) + ea[c];
            r = 1;
        }
        float4 q0, q1, q2, q3;
        if (r + 0 < CH) q0 = base[(r + 0) * 64];
        if (r + 1 < CH) q1 = base[(r + 1) * 64];
        if (r + 2 < CH) q2 = base[(r + 2) * 64];
        if (r + 3 < CH) q3 = base[(r + 3) * 64];
        while (r + 4 <= CH) {
            float4 e0 = q0, e1 = q1, e2 = q2, e3 = q3;
            if (r + 4 < CH) q0 = base[(r + 4) * 64];
            if (r + 5 < CH) q1 = base[(r + 5) * 64];
            if (r + 6 < CH) q2 = base[(r + 6) * 64];
            if (r + 7 < CH) q3 = base[(r + 7) * 64];
            hmm_step(rr, e0);
            hmm_step(rr, e1);
            hmm_step(rr, e2);
            hmm_step(rr, e3);
            r += 4;
        }
        if (r + 0 < CH) hmm_step(rr, q0);
        if (r + 1 < CH) hmm_step(rr, q1);
        if (r + 2 < CH) hmm_step(rr, q2);
    };

    if (wave > 0) fill(0);
    __syncthreads();
    for (int k = 0; k < NCH; ++k) {
        if (wave > 0) {
            if (k + 1 < NCH) fill(k + 1);
        } else {
            consume(k);
        }
        __syncthreads();
    }

    if (wave == 0) {
        float a[4];
#pragma unroll
        for (int c = 0; c < 4; ++c)
            a[c] = rr[c] + ((4 * lane + c == Uv - 1) ? 0.0f : 1.0f);
        float r2 = l2add(l2add(a[0], a[1]), l2add(a[2], a[3]));
#pragma unroll
        for (int o = 32; o >= 1; o >>= 1) {
            float t = __shfl_xor(r2, o, 64);
            r2 = l2add(r2, t);
        }
        if (lane == 0) out[b] = r2 * LN2_F;
    }
}

extern "C" void kernel_launch(void* const* d_in, const int* in_sizes, int n_in,
                              void* d_out, int out_size, void* d_ws, size_t ws_size,
                              hipStream_t stream) {
    const float* lp = (const float*)d_in[0];
    const float* lens = (const float*)d_in[1];
    const int* phns = (const int*)d_in[2];
    const float* phn_lens = (const float*)d_in[3];
    float* out = (float*)d_out;
    (void)in_sizes; (void)n_in; (void)out_size;

    const size_t need = (size_t)Bc * Tc * Uc * sizeof(float); // 65.5 MB
    if (d_ws != nullptr && ws_size >= need) {
        float* e2 = (float*)d_ws;
        gather_kernel<<<dim3(Bc, GBLK), 256, 0, stream>>>(lp, lens, phns,
                                                          phn_lens, e2);
        scan_kernel<<<Bc, 128, 0, stream>>>(e2, phn_lens, out);
    } else {
        fused_hmm_kernel<<<Bc, 512, 0, stream>>>(lp, lens, phns, phn_lens, out);
    }
}

// Round 4
// 280.572 us; speedup vs baseline: 1.1474x; 1.0325x over previous
//
#include <hip/hip_runtime.h>
#include <math.h>

// Problem dims (fixed by setup_inputs)
constexpr int Bc = 64;
constexpr int Tc = 1000;
constexpr int Vc = 512;
constexpr int Uc = 256;
constexpr int CH = 50;        // t-rows per LDS chunk (scan)
constexpr int NCH = Tc / CH;  // 20 chunks
constexpr int PW = 7;         // fused fallback: producer waves
constexpr int SLOTS = 4;      // fused fallback: stage slots per producer wave

// gather kernel geometry
constexpr int GW = 2;            // waves per gather block
constexpr int GNR = 10;          // rows (slots) per wave, all in flight at once
constexpr int GROWS = GW * GNR;  // 20 rows per gather block
constexpr int GBLK = Tc / GROWS; // 50 gather blocks per batch elem

#define NEG_INF_F (-100000.0f)
#define LOG2E_F 1.44269504088896340736f
#define LN2_F 0.69314718055994530942f
#define DEAD_F (-1.0e9f)

// raw v_exp_f32 (2^x) / v_log_f32 (log2 x)
__device__ __forceinline__ float fexp2(float x) {
#if __has_builtin(__builtin_amdgcn_exp2f)
    return __builtin_amdgcn_exp2f(x);
#else
    return __expf(x * LN2_F);
#endif
}
__device__ __forceinline__ float flog2(float x) {
#if __has_builtin(__builtin_amdgcn_logf)
    return __builtin_amdgcn_logf(x);
#else
    return __logf(x) * LOG2E_F;
#endif
}

// log2-domain logadd: log2(2^x + 2^y) (fallback kernel only)
__device__ __forceinline__ float l2add(float x, float y) {
    float m = fmaxf(x, y);
    float p = fexp2(-fabsf(x - y));
    return m + flog2(1.0f + p);
}

// Whole-wave shift-up-by-1 via DPP wave_shr:1 (VALU op).
// Lane n gets lane n-1's x; lane 0 gets `lane0val` (bound_ctrl=false -> old).
__device__ __forceinline__ float waveshr1(float x, float lane0val) {
    return __int_as_float(__builtin_amdgcn_update_dpp(
        __float_as_int(lane0val), __float_as_int(x),
        0x138 /* wave_shr:1 */, 0xF, 0xF, false));
}

// f64 variant: shift both 32-bit halves; lane 0 receives +0.0.
__device__ __forceinline__ double waveshr1_f64(double x) {
    int lo = __double2loint(x), hi = __double2hiint(x);
    int slo = __builtin_amdgcn_update_dpp(0, lo, 0x138, 0xF, 0xF, false);
    int shi = __builtin_amdgcn_update_dpp(0, hi, 0x138, 0xF, 0xF, false);
    return __hiloint2double(shi, slo);
}

// LINEAR-domain HMM step in f64 (scaled forward algorithm):
//   r_i(t) = (r_i(t-1) + r_{i-1}(t-1)) * EL_i(t)
// f64 needed: cross-state spread reaches ~2^-800 below the running max
// (free self-loop on the last state); f32 denormal-flushes the eventual
// winner's prefix (round-3 failure, absmax 13). cvts are off the dep chain.
__device__ __forceinline__ void hmm_step_f64(double rr[4], const float4 ev) {
    double nb0 = waveshr1_f64(rr[3]); // lane0: no predecessor -> 0
    double s0 = rr[0] + nb0;
    double s1 = rr[1] + rr[0];
    double s2 = rr[2] + rr[1];
    double s3 = rr[3] + rr[2];
    rr[0] = s0 * (double)ev.x;
    rr[1] = s1 * (double)ev.y;
    rr[2] = s2 * (double)ev.z;
    rr[3] = s3 * (double)ev.w;
}

// log2-domain HMM step (fallback kernel only)
__device__ __forceinline__ void hmm_step(float rr[4], const float4 ev) {
    float nb0 = waveshr1(rr[3], DEAD_F);
    float e[4] = {ev.x, ev.y, ev.z, ev.w};
    float nb[4] = {nb0, rr[0], rr[1], rr[2]};
#pragma unroll
    for (int c = 0; c < 4; ++c) {
        float x = rr[c], y = nb[c];
        float m = fmaxf(x, y);
        float p = fexp2(-fabsf(x - y));
        float me = m + e[c];
        rr[c] = me + flog2(1.0f + p);
    }
}

// async global->LDS DMA of 16 B/lane (1 KB per wave-instruction)
__device__ __forceinline__ void dma16(const float* gsrc, float* lds, int lane) {
    typedef const __attribute__((address_space(1))) unsigned int* gp_t;
    typedef __attribute__((address_space(3))) unsigned int* lp_t;
    __builtin_amdgcn_global_load_lds((gp_t)(const void*)(gsrc + 4 * lane),
                                     (lp_t)(void*)lds, 16, 0, 0);
}

// ---------------------------------------------------------------------------
// Kernel A: gather + transform emissions to LINEAR domain EL[b][t][u].
// EL = 2^(lp*log2e + off); masked (u>=Uv or t>=Tv) -> 0.
// Counted-vmcnt pipeline: all 20 row-loads in flight, vmcnt(10) -> process
// rows 0..4, vmcnt(0) -> process rows 5..9 (no empty-queue drains).
// ---------------------------------------------------------------------------
__global__ __launch_bounds__(128, 2) void gather_kernel(
    const float* __restrict__ lp, const float* __restrict__ lens,
    const int* __restrict__ phns, const float* __restrict__ phn_lens,
    float* __restrict__ el) {
    __shared__ float stage[GW][GNR][Vc]; // 40 KB -> 4 blocks/CU
    const int b = blockIdx.x;
    const int t0 = blockIdx.y * GROWS;
    const int tid = threadIdx.x;
    const int wave = tid >> 6;
    const int lane = tid & 63;
    const int Tv = (int)rintf(lens[b] * (float)Tc);
    const int Uv = (int)rintf(phn_lens[b] * (float)Uc);
    const float* lpb = lp + (size_t)b * Tc * Vc;
    float* elb = el + ((size_t)b * Tc + t0) * Uc;

    int col[4];
    float off[4];
    bool pv[4];
    int4 cc = *(const int4*)(phns + (size_t)b * Uc + 4 * lane);
    int c4[4] = {cc.x, cc.y, cc.z, cc.w};
#pragma unroll
    for (int c = 0; c < 4; ++c) {
        int v = c4[c];
        v = v < 0 ? 0 : (v > Vc - 1 ? Vc - 1 : v);
        col[c] = v;
        int i = 4 * lane + c;
        pv[c] = (i < Uv);
        off[c] = (i == Uv - 1) ? 0.0f : -1.0f; // transition const (log2 units)
    }

    float* stw = &stage[wave][0][0];
    // issue ALL row loads (2 x dma16 per row, 20 vmem ops in flight)
#pragma unroll
    for (int j = 0; j < GNR; ++j) {
        int r = wave + j * GW;
        const float* gsrc = lpb + (size_t)(t0 + r) * Vc;
        float* st = stw + j * Vc;
        dma16(gsrc, st, lane);             // floats [0..255]
        dma16(gsrc + 256, st + 256, lane); // floats [256..511]
    }

    auto do_rows = [&](int j0) {
#pragma unroll
        for (int j = j0; j < j0 + GNR / 2; ++j) {
            int r = wave + j * GW;
            const bool tv = (t0 + r) < Tv;
            const float* st = stw + j * Vc;
            float ev[4];
#pragma unroll
            for (int c = 0; c < 4; ++c) {
                float e = st[col[c]]; // random-bank ds_read_b32 (cheap)
                ev[c] = (pv[c] && tv) ? fexp2(fmaf(e, LOG2E_F, off[c])) : 0.0f;
            }
            *(float4*)(elb + (size_t)r * Uc + 4 * lane) =
                make_float4(ev[0], ev[1], ev[2], ev[3]);
        }
    };

    __builtin_amdgcn_s_waitcnt(0x0f7A); // vmcnt(10): first 10 loads landed
    do_rows(0);
    __builtin_amdgcn_s_waitcnt(0x0f70); // vmcnt(0): rest landed (+ stores drain)
    do_rows(GNR / 2);
}

// ---------------------------------------------------------------------------
// Kernel B: sequential linear-domain f64 scan over precomputed f32 EL.
// SINGLE wave per block: issues next-chunk DMA, consumes current chunk from
// LDS, syncs on vmcnt only (no barriers). Per-chunk rescale by an EXACT
// power of two (wave-wide butterfly max, exponent-field bit surgery).
// ---------------------------------------------------------------------------
__global__ __launch_bounds__(64, 1) void scan_kernel(
    const float* __restrict__ el, const float* __restrict__ phn_lens,
    float* __restrict__ out) {
    __shared__ float ebuf[2][CH][Uc]; // 100 KB double buffer
    const int b = blockIdx.x;
    const int lane = threadIdx.x & 63;
    const int Uv = (int)rintf(phn_lens[b] * (float)Uc);
    const float* eb = el + (size_t)b * Tc * Uc;
    double rr[4];
    float S = 0.0f; // accumulated log2 scale (integer-valued, exact in f32)

    auto fill = [&](int k) {
        const float* src = eb + (size_t)k * CH * Uc;
        float* dst = &ebuf[k & 1][0][0];
#pragma unroll 5
        for (int r = 0; r < CH; ++r)
            dma16(src + (size_t)r * Uc, dst + r * Uc, lane); // 1 row = 1 KB
    };

    auto consume = [&](int k) {
        const float4* base = (const float4*)&ebuf[k & 1][0][0] + lane;
        int r = 0;
        if (k == 0) {
            float4 e0 = base[0];
            float ea[4] = {e0.x, e0.y, e0.z, e0.w};
#pragma unroll
            for (int c = 0; c < 4; ++c)
                rr[c] = (4 * lane + c == 0) ? (double)ea[c] : 0.0; // pi*EL(0)
            r = 1;
        }
        float4 q0, q1, q2, q3;
        if (r + 0 < CH) q0 = base[(r + 0) * 64];
        if (r + 1 < CH) q1 = base[(r + 1) * 64];
        if (r + 2 < CH) q2 = base[(r + 2) * 64];
        if (r + 3 < CH) q3 = base[(r + 3) * 64];
        while (r + 4 <= CH) {
            float4 e0 = q0, e1 = q1, e2v = q2, e3 = q3;
            if (r + 4 < CH) q0 = base[(r + 4) * 64];
            if (r + 5 < CH) q1 = base[(r + 5) * 64];
            if (r + 6 < CH) q2 = base[(r + 6) * 64];
            if (r + 7 < CH) q3 = base[(r + 7) * 64];
            hmm_step_f64(rr, e0);
            hmm_step_f64(rr, e1);
            hmm_step_f64(rr, e2v);
            hmm_step_f64(rr, e3);
            r += 4;
        }
        if (r + 0 < CH) hmm_step_f64(rr, q0);
        if (r + 1 < CH) hmm_step_f64(rr, q1);
        if (r + 2 < CH) hmm_step_f64(rr, q2);
    };

    fill(0);
    __builtin_amdgcn_s_waitcnt(0x0f70); // vmcnt(0)
    for (int k = 0; k < NCH; ++k) {
        if (k + 1 < NCH) fill(k + 1); // issue next chunk's DMAs (overlap)
        consume(k);
        // --- rescale by exact power of two (uniform across wave) ---
        double m = fmax(fmax(rr[0], rr[1]), fmax(rr[2], rr[3]));
#pragma unroll
        for (int o = 32; o >= 1; o >>= 1) m = fmax(m, __shfl_xor(m, o, 64));
        if (m > 0.0) {
            int ik = ((__double2hiint(m) >> 20) & 0x7ff) - 1023; // ilogb(m)
            S += (float)ik;
            const double sc = __hiloint2double((1023 - ik) << 20, 0); // 2^-ik
            rr[0] *= sc; rr[1] *= sc; rr[2] *= sc; rr[3] *= sc;
        }
        __builtin_amdgcn_s_waitcnt(0x0f70); // next buffer ready
    }

    // undo per-state shift (x2 on non-last states), sum, back to nats
    double a = 0.0;
#pragma unroll
    for (int c = 0; c < 4; ++c)
        a += rr[c] * ((4 * lane + c == Uv - 1) ? 1.0 : 2.0);
#pragma unroll
    for (int o = 32; o >= 1; o >>= 1) a += __shfl_xor(a, o, 64);
    if (lane == 0) out[b] = (flog2((float)a) + S) * LN2_F;
}

// ---------------------------------------------------------------------------
// Fallback: fused single-kernel log2-domain version (workspace too small).
// This version passed verification (absmax 0.0) in earlier rounds.
// ---------------------------------------------------------------------------
__global__ __launch_bounds__(512, 1) void fused_hmm_kernel(
    const float* __restrict__ lp, const float* __restrict__ lens,
    const int* __restrict__ phns, const float* __restrict__ phn_lens,
    float* __restrict__ out) {
    __shared__ float ebuf[2][CH][Uc];      // 100 KB
    __shared__ float stage[PW][SLOTS][Vc]; // 56 KB
    const int b = blockIdx.x;
    const int tid = threadIdx.x;
    const int wave = tid >> 6;
    const int lane = tid & 63;
    const int Tv = (int)rintf(lens[b] * (float)Tc);
    const int Uv = (int)rintf(phn_lens[b] * (float)Uc);
    const float* lpb = lp + (size_t)b * Tc * Vc;

    int col[4];
    float off[4];
    bool pv[4];
    float rr[4];

    if (wave > 0) {
        int4 cc = *(const int4*)(phns + (size_t)b * Uc + 4 * lane);
        int c4[4] = {cc.x, cc.y, cc.z, cc.w};
#pragma unroll
        for (int c = 0; c < 4; ++c) {
            int v = c4[c];
            v = v < 0 ? 0 : (v > Vc - 1 ? Vc - 1 : v);
            col[c] = v;
            int i = 4 * lane + c;
            pv[c] = (i < Uv);
            off[c] = (i == Uv - 1) ? 0.0f : -1.0f;
        }
    }

    auto fill = [&](int k) {
        float* dst = &ebuf[k & 1][0][0];
        const int tb = k * CH;
        const int r0 = wave - 1;
        float* stw = &stage[wave - 1][0][0];
#pragma unroll
        for (int half = 0; half < 2; ++half) {
#pragma unroll
            for (int jj = 0; jj < SLOTS; ++jj) {
                int r = r0 + (half * SLOTS + jj) * PW;
                if (r < CH) {
                    const float* gsrc = lpb + (size_t)(tb + r) * Vc;
                    float* st = stw + jj * Vc;
                    dma16(gsrc, st, lane);
                    dma16(gsrc + 256, st + 256, lane);
                }
            }
            __builtin_amdgcn_s_waitcnt(0x0f70);
#pragma unroll
            for (int jj = 0; jj < SLOTS; ++jj) {
                int r = r0 + (half * SLOTS + jj) * PW;
                if (r < CH) {
                    const bool tv = (tb + r) < Tv;
                    const float* st = stw + jj * Vc;
                    float ev[4];
#pragma unroll
                    for (int c = 0; c < 4; ++c) {
                        float e = st[col[c]];
                        ev[c] = (pv[c] && tv) ? fmaf(e, LOG2E_F, off[c])
                                              : (NEG_INF_F * LOG2E_F + off[c]);
                    }
                    *(float4*)(dst + r * Uc + 4 * lane) =
                        make_float4(ev[0], ev[1], ev[2], ev[3]);
                }
            }
        }
    };

    auto consume = [&](int k) {
        const float4* base = (const float4*)&ebuf[k & 1][0][0] + lane;
        int r = 0;
        if (k == 0) {
            float4 e0 = base[0];
            float ea[4] = {e0.x, e0.y, e0.z, e0.w};
#pragma unroll
            for (int c = 0; c < 4; ++c)
                rr[c] = ((4 * lane + c == 0) ? 0.0f : DEAD_F) + ea[c];
            r = 1;
        }
        float4 q0, q1, q2, q3;
        if (r + 0 < CH) q0 = base[(r + 0) * 64];
        if (r + 1 < CH) q1 = base[(r + 1) * 64];
        if (r + 2 < CH) q2 = base[(r + 2) * 64];
        if (r + 3 < CH) q3 = base[(r + 3) * 64];
        while (r + 4 <= CH) {
            float4 e0 = q0, e1 = q1, e2 = q2, e3 = q3;
            if (r + 4 < CH) q0 = base[(r + 4) * 64];
            if (r + 5 < CH) q1 = base[(r + 5) * 64];
            if (r + 6 < CH) q2 = base[(r + 6) * 64];
            if (r + 7 < CH) q3 = base[(r + 7) * 64];
            hmm_step(rr, e0);
            hmm_step(rr, e1);
            hmm_step(rr, e2);
            hmm_step(rr, e3);
            r += 4;
        }
        if (r + 0 < CH) hmm_step(rr, q0);
        if (r + 1 < CH) hmm_step(rr, q1);
        if (r + 2 < CH) hmm_step(rr, q2);
    };

    if (wave > 0) fill(0);
    __syncthreads();
    for (int k = 0; k < NCH; ++k) {
        if (wave > 0) {
            if (k + 1 < NCH) fill(k + 1);
        } else {
            consume(k);
        }
        __syncthreads();
    }

    if (wave == 0) {
        float a[4];
#pragma unroll
        for (int c = 0; c < 4; ++c)
            a[c] = rr[c] + ((4 * lane + c == Uv - 1) ? 0.0f : 1.0f);
        float r2 = l2add(l2add(a[0], a[1]), l2add(a[2], a[3]));
#pragma unroll
        for (int o = 32; o >= 1; o >>= 1) {
            float t = __shfl_xor(r2, o, 64);
            r2 = l2add(r2, t);
        }
        if (lane == 0) out[b] = r2 * LN2_F;
    }
}

extern "C" void kernel_launch(void* const* d_in, const int* in_sizes, int n_in,
                              void* d_out, int out_size, void* d_ws, size_t ws_size,
                              hipStream_t stream) {
    const float* lp = (const float*)d_in[0];
    const float* lens = (const float*)d_in[1];
    const int* phns = (const int*)d_in[2];
    const float* phn_lens = (const float*)d_in[3];
    float* out = (float*)d_out;
    (void)in_sizes; (void)n_in; (void)out_size;

    const size_t need = (size_t)Bc * Tc * Uc * sizeof(float); // 65.5 MB
    if (d_ws != nullptr && ws_size >= need) {
        float* el = (float*)d_ws;
        gather_kernel<<<dim3(Bc, GBLK), 128, 0, stream>>>(lp, lens, phns,
                                                          phn_lens, el);
        scan_kernel<<<Bc, 64, 0, stream>>>(el, phn_lens, out);
    } else {
        fused_hmm_kernel<<<Bc, 512, 0, stream>>>(lp, lens, phns, phn_lens, out);
    }
}

// Round 5
// 277.054 us; speedup vs baseline: 1.1619x; 1.0127x over previous
//
#include <hip/hip_runtime.h>
#include <math.h>

// Problem dims (fixed by setup_inputs)
constexpr int Bc = 64;
constexpr int Tc = 1000;
constexpr int Vc = 512;
constexpr int Uc = 256;
constexpr int CH = 50;        // t-rows per LDS chunk (scan)
constexpr int NCH = Tc / CH;  // 20 chunks
constexpr int PW = 7;         // fused fallback: producer waves
constexpr int SLOTS = 4;      // fused fallback: stage slots per producer wave

// gather kernel geometry
constexpr int GW = 2;            // waves per gather block
constexpr int GNR = 10;          // rows (slots) per wave, all in flight at once
constexpr int GROWS = GW * GNR;  // 20 rows per gather block
constexpr int GBLK = Tc / GROWS; // 50 gather blocks per batch elem

#define NEG_INF_F (-100000.0f)
#define LOG2E_F 1.44269504088896340736f
#define LN2_F 0.69314718055994530942f
#define DEAD_F (-1.0e9f)
#define EBIAS 30  // renorm target: lane max ~2^30 (up-room 97b, down-room 179b)

// raw v_exp_f32 (2^x) / v_log_f32 (log2 x)
__device__ __forceinline__ float fexp2(float x) {
#if __has_builtin(__builtin_amdgcn_exp2f)
    return __builtin_amdgcn_exp2f(x);
#else
    return __expf(x * LN2_F);
#endif
}
__device__ __forceinline__ float flog2(float x) {
#if __has_builtin(__builtin_amdgcn_logf)
    return __builtin_amdgcn_logf(x);
#else
    return __logf(x) * LOG2E_F;
#endif
}

// log2-domain logadd: log2(2^x + 2^y)
__device__ __forceinline__ float l2add(float x, float y) {
    float m = fmaxf(x, y);
    float p = fexp2(-fabsf(x - y));
    return m + flog2(1.0f + p);
}

// Whole-wave shift-up-by-1 via DPP wave_shr:1 (full-rate VALU op).
// Lane n gets lane n-1's x; lane 0 gets `lane0val` (bound_ctrl=false -> old).
__device__ __forceinline__ float waveshr1(float x, float lane0val) {
    return __int_as_float(__builtin_amdgcn_update_dpp(
        __float_as_int(lane0val), __float_as_int(x),
        0x138 /* wave_shr:1 */, 0xF, 0xF, false));
}
__device__ __forceinline__ int waveshr1_i(int x) {
    return __builtin_amdgcn_update_dpp(x, x, 0x138, 0xF, 0xF, false);
    // lane 0 keeps its own value (old = x)
}

// LINEAR-domain HMM step, f32 mantissa with per-lane scale (true value =
// rr * 2^e). Cross-lane link rescaled by sc_d = 2^(e_left - e), which is
// loop-invariant between renorms. 10 full-rate VALU ops, no transcendentals,
// no f64 (f64 issue cost was the round-4 bottleneck: 195 cy/step).
__device__ __forceinline__ void hmm_step_f32(float rr[4], const float4 ev,
                                             float sc_d) {
    float nb0 = waveshr1(rr[3], 0.0f) * sc_d; // lane0: no predecessor -> 0
    float s0 = rr[0] + nb0;
    float s1 = rr[1] + rr[0];
    float s2 = rr[2] + rr[1];
    float s3 = rr[3] + rr[2];
    rr[0] = s0 * ev.x;
    rr[1] = s1 * ev.y;
    rr[2] = s2 * ev.z;
    rr[3] = s3 * ev.w;
}

// log2-domain HMM step (fallback kernel only)
__device__ __forceinline__ void hmm_step(float rr[4], const float4 ev) {
    float nb0 = waveshr1(rr[3], DEAD_F);
    float e[4] = {ev.x, ev.y, ev.z, ev.w};
    float nb[4] = {nb0, rr[0], rr[1], rr[2]};
#pragma unroll
    for (int c = 0; c < 4; ++c) {
        float x = rr[c], y = nb[c];
        float m = fmaxf(x, y);
        float p = fexp2(-fabsf(x - y));
        float me = m + e[c];
        rr[c] = me + flog2(1.0f + p);
    }
}

// async global->LDS DMA of 16 B/lane (1 KB per wave-instruction)
__device__ __forceinline__ void dma16(const float* gsrc, float* lds, int lane) {
    typedef const __attribute__((address_space(1))) unsigned int* gp_t;
    typedef __attribute__((address_space(3))) unsigned int* lp_t;
    __builtin_amdgcn_global_load_lds((gp_t)(const void*)(gsrc + 4 * lane),
                                     (lp_t)(void*)lds, 16, 0, 0);
}

// ---------------------------------------------------------------------------
// Kernel A: gather + transform emissions to LINEAR domain EL[b][t][u].
// EL = 2^(lp*log2e + off); masked (u>=Uv or t>=Tv) -> 0.
// ---------------------------------------------------------------------------
__global__ __launch_bounds__(128, 2) void gather_kernel(
    const float* __restrict__ lp, const float* __restrict__ lens,
    const int* __restrict__ phns, const float* __restrict__ phn_lens,
    float* __restrict__ el) {
    __shared__ float stage[GW][GNR][Vc]; // 40 KB -> 4 blocks/CU
    const int b = blockIdx.x;
    const int t0 = blockIdx.y * GROWS;
    const int tid = threadIdx.x;
    const int wave = tid >> 6;
    const int lane = tid & 63;
    const int Tv = (int)rintf(lens[b] * (float)Tc);
    const int Uv = (int)rintf(phn_lens[b] * (float)Uc);
    const float* lpb = lp + (size_t)b * Tc * Vc;
    float* elb = el + ((size_t)b * Tc + t0) * Uc;

    int col[4];
    float off[4];
    bool pv[4];
    int4 cc = *(const int4*)(phns + (size_t)b * Uc + 4 * lane);
    int c4[4] = {cc.x, cc.y, cc.z, cc.w};
#pragma unroll
    for (int c = 0; c < 4; ++c) {
        int v = c4[c];
        v = v < 0 ? 0 : (v > Vc - 1 ? Vc - 1 : v);
        col[c] = v;
        int i = 4 * lane + c;
        pv[c] = (i < Uv);
        off[c] = (i == Uv - 1) ? 0.0f : -1.0f; // transition const (log2 units)
    }

    float* stw = &stage[wave][0][0];
    // issue ALL row loads (2 x dma16 per row, 20 vmem ops in flight)
#pragma unroll
    for (int j = 0; j < GNR; ++j) {
        int r = wave + j * GW;
        const float* gsrc = lpb + (size_t)(t0 + r) * Vc;
        float* st = stw + j * Vc;
        dma16(gsrc, st, lane);             // floats [0..255]
        dma16(gsrc + 256, st + 256, lane); // floats [256..511]
    }

    auto do_rows = [&](int j0) {
#pragma unroll
        for (int j = j0; j < j0 + GNR / 2; ++j) {
            int r = wave + j * GW;
            const bool tv = (t0 + r) < Tv;
            const float* st = stw + j * Vc;
            float ev[4];
#pragma unroll
            for (int c = 0; c < 4; ++c) {
                float e = st[col[c]]; // random-bank ds_read_b32 (cheap)
                ev[c] = (pv[c] && tv) ? fexp2(fmaf(e, LOG2E_F, off[c])) : 0.0f;
            }
            *(float4*)(elb + (size_t)r * Uc + 4 * lane) =
                make_float4(ev[0], ev[1], ev[2], ev[3]);
        }
    };

    __builtin_amdgcn_s_waitcnt(0x0f7A); // vmcnt(10): first 10 loads landed
    do_rows(0);
    __builtin_amdgcn_s_waitcnt(0x0f70); // vmcnt(0): rest landed
    do_rows(GNR / 2);
}

// ---------------------------------------------------------------------------
// Kernel B: sequential linear-domain scan, f32 mantissa + per-lane exponent.
// SINGLE wave per block; next-chunk DMA overlapped, vmcnt-only sync.
// Renorm every 4 steps: lane max -> ~2^EBIAS, exact pow2 scaling (exponent
// bit surgery); zero lanes ADOPT left neighbor's exponent (frontier moves
// 1 lane per 4 steps = 1 renorm period, so adopted e is never stale).
// ---------------------------------------------------------------------------
__global__ __launch_bounds__(64, 1) void scan_kernel(
    const float* __restrict__ el, const float* __restrict__ phn_lens,
    float* __restrict__ out) {
    __shared__ float ebuf[2][CH][Uc]; // 100 KB double buffer
    const int b = blockIdx.x;
    const int lane = threadIdx.x & 63;
    const int Uv = (int)rintf(phn_lens[b] * (float)Uc);
    const float* eb = el + (size_t)b * Tc * Uc;
    float rr[4];
    int e = 0;         // per-lane scale: true value = rr * 2^e
    float sc_d = 1.0f; // 2^(e_left - e), refreshed at each renorm

    auto fill = [&](int k) {
        const float* src = eb + (size_t)k * CH * Uc;
        float* dst = &ebuf[k & 1][0][0];
#pragma unroll 5
        for (int r = 0; r < CH; ++r)
            dma16(src + (size_t)r * Uc, dst + r * Uc, lane); // 1 row = 1 KB
    };

    auto renorm = [&]() {
        float m = fmaxf(fmaxf(rr[0], rr[1]), fmaxf(rr[2], rr[3]));
        int ep_old = waveshr1_i(e); // left neighbor's e (lane0: own)
        bool nz = (m > 0.0f);
        int ik = ((__float_as_int(m) >> 23) & 255) - 127 - EBIAS;
        ik = ik < -96 ? -96 : (ik > 96 ? 96 : ik); // denormal/overflow guard
        const float sc = __int_as_float((127 - ik) << 23); // exact 2^-ik
        rr[0] *= sc; rr[1] *= sc; rr[2] *= sc; rr[3] *= sc; // 0*sc = 0 ok
        e = nz ? (e + ik) : ep_old; // zero lanes adopt left's exponent
        int ep = waveshr1_i(e);
        int d = ep - e;
        int dc = d < -126 ? -126 : (d > 127 ? 127 : d);
        float sd = __int_as_float((127 + dc) << 23); // exact 2^d
        // d < -126: incoming mass < 2^-149 of this lane's scale -> truly 0
        sc_d = (d < -126) ? 0.0f : sd;
    };

    auto consume = [&](int k) {
        const float4* base = (const float4*)&ebuf[k & 1][0][0] + lane;
        int r = 0;
        if (k == 0) {
            float4 e0 = base[0];
            float ea[4] = {e0.x, e0.y, e0.z, e0.w};
#pragma unroll
            for (int c = 0; c < 4; ++c)
                rr[c] = (4 * lane + c == 0) ? ea[c] : 0.0f; // pi * EL(0)
            r = 1;
        }
        float4 q0, q1, q2, q3;
        if (r + 0 < CH) q0 = base[(r + 0) * 64];
        if (r + 1 < CH) q1 = base[(r + 1) * 64];
        if (r + 2 < CH) q2 = base[(r + 2) * 64];
        if (r + 3 < CH) q3 = base[(r + 3) * 64];
        while (r + 4 <= CH) {
            float4 e0 = q0, e1 = q1, e2v = q2, e3 = q3;
            if (r + 4 < CH) q0 = base[(r + 4) * 64];
            if (r + 5 < CH) q1 = base[(r + 5) * 64];
            if (r + 6 < CH) q2 = base[(r + 6) * 64];
            if (r + 7 < CH) q3 = base[(r + 7) * 64];
            hmm_step_f32(rr, e0, sc_d);
            hmm_step_f32(rr, e1, sc_d);
            hmm_step_f32(rr, e2v, sc_d);
            hmm_step_f32(rr, e3, sc_d);
            renorm(); // every 4 steps: drift <= ~40 bits << 97-bit headroom
            r += 4;
        }
        bool tail = false;
        if (r + 0 < CH) { hmm_step_f32(rr, q0, sc_d); tail = true; }
        if (r + 1 < CH) { hmm_step_f32(rr, q1, sc_d); }
        if (r + 2 < CH) { hmm_step_f32(rr, q2, sc_d); }
        if (tail) renorm();
    };

    fill(0);
    __builtin_amdgcn_s_waitcnt(0x0f70); // vmcnt(0)
    for (int k = 0; k < NCH; ++k) {
        if (k + 1 < NCH) fill(k + 1); // issue next chunk's DMAs (overlap)
        consume(k);
        __builtin_amdgcn_s_waitcnt(0x0f70); // next buffer ready
    }

    // undo per-state shift (x2 on non-last states), per-lane log2 + e,
    // then wave-wide logsumexp (log2 domain), back to nats.
    float a = 0.0f;
#pragma unroll
    for (int c = 0; c < 4; ++c)
        a += rr[c] * ((4 * lane + c == Uv - 1) ? 1.0f : 2.0f);
    float v = (a > 0.0f) ? (flog2(a) + (float)e) : -1.0e30f;
#pragma unroll
    for (int o = 32; o >= 1; o >>= 1) {
        float t = __shfl_xor(v, o, 64);
        v = l2add(v, t);
    }
    if (lane == 0) out[b] = v * LN2_F;
}

// ---------------------------------------------------------------------------
// Fallback: fused single-kernel log2-domain version (workspace too small).
// Passed verification (absmax 0.0) in earlier rounds.
// ---------------------------------------------------------------------------
__global__ __launch_bounds__(512, 1) void fused_hmm_kernel(
    const float* __restrict__ lp, const float* __restrict__ lens,
    const int* __restrict__ phns, const float* __restrict__ phn_lens,
    float* __restrict__ out) {
    __shared__ float ebuf[2][CH][Uc];      // 100 KB
    __shared__ float stage[PW][SLOTS][Vc]; // 56 KB
    const int b = blockIdx.x;
    const int tid = threadIdx.x;
    const int wave = tid >> 6;
    const int lane = tid & 63;
    const int Tv = (int)rintf(lens[b] * (float)Tc);
    const int Uv = (int)rintf(phn_lens[b] * (float)Uc);
    const float* lpb = lp + (size_t)b * Tc * Vc;

    int col[4];
    float off[4];
    bool pv[4];
    float rr[4];

    if (wave > 0) {
        int4 cc = *(const int4*)(phns + (size_t)b * Uc + 4 * lane);
        int c4[4] = {cc.x, cc.y, cc.z, cc.w};
#pragma unroll
        for (int c = 0; c < 4; ++c) {
            int v = c4[c];
            v = v < 0 ? 0 : (v > Vc - 1 ? Vc - 1 : v);
            col[c] = v;
            int i = 4 * lane + c;
            pv[c] = (i < Uv);
            off[c] = (i == Uv - 1) ? 0.0f : -1.0f;
        }
    }

    auto fill = [&](int k) {
        float* dst = &ebuf[k & 1][0][0];
        const int tb = k * CH;
        const int r0 = wave - 1;
        float* stw = &stage[wave - 1][0][0];
#pragma unroll
        for (int half = 0; half < 2; ++half) {
#pragma unroll
            for (int jj = 0; jj < SLOTS; ++jj) {
                int r = r0 + (half * SLOTS + jj) * PW;
                if (r < CH) {
                    const float* gsrc = lpb + (size_t)(tb + r) * Vc;
                    float* st = stw + jj * Vc;
                    dma16(gsrc, st, lane);
                    dma16(gsrc + 256, st + 256, lane);
                }
            }
            __builtin_amdgcn_s_waitcnt(0x0f70);
#pragma unroll
            for (int jj = 0; jj < SLOTS; ++jj) {
                int r = r0 + (half * SLOTS + jj) * PW;
                if (r < CH) {
                    const bool tv = (tb + r) < Tv;
                    const float* st = stw + jj * Vc;
                    float ev[4];
#pragma unroll
                    for (int c = 0; c < 4; ++c) {
                        float e = st[col[c]];
                        ev[c] = (pv[c] && tv) ? fmaf(e, LOG2E_F, off[c])
                                              : (NEG_INF_F * LOG2E_F + off[c]);
                    }
                    *(float4*)(dst + r * Uc + 4 * lane) =
                        make_float4(ev[0], ev[1], ev[2], ev[3]);
                }
            }
        }
    };

    auto consume = [&](int k) {
        const float4* base = (const float4*)&ebuf[k & 1][0][0] + lane;
        int r = 0;
        if (k == 0) {
            float4 e0 = base[0];
            float ea[4] = {e0.x, e0.y, e0.z, e0.w};
#pragma unroll
            for (int c = 0; c < 4; ++c)
                rr[c] = ((4 * lane + c == 0) ? 0.0f : DEAD_F) + ea[c];
            r = 1;
        }
        float4 q0, q1, q2, q3;
        if (r + 0 < CH) q0 = base[(r + 0) * 64];
        if (r + 1 < CH) q1 = base[(r + 1) * 64];
        if (r + 2 < CH) q2 = base[(r + 2) * 64];
        if (r + 3 < CH) q3 = base[(r + 3) * 64];
        while (r + 4 <= CH) {
            float4 e0 = q0, e1 = q1, e2 = q2, e3 = q3;
            if (r + 4 < CH) q0 = base[(r + 4) * 64];
            if (r + 5 < CH) q1 = base[(r + 5) * 64];
            if (r + 6 < CH) q2 = base[(r + 6) * 64];
            if (r + 7 < CH) q3 = base[(r + 7) * 64];
            hmm_step(rr, e0);
            hmm_step(rr, e1);
            hmm_step(rr, e2);
            hmm_step(rr, e3);
            r += 4;
        }
        if (r + 0 < CH) hmm_step(rr, q0);
        if (r + 1 < CH) hmm_step(rr, q1);
        if (r + 2 < CH) hmm_step(rr, q2);
    };

    if (wave > 0) fill(0);
    __syncthreads();
    for (int k = 0; k < NCH; ++k) {
        if (wave > 0) {
            if (k + 1 < NCH) fill(k + 1);
        } else {
            consume(k);
        }
        __syncthreads();
    }

    if (wave == 0) {
        float a[4];
#pragma unroll
        for (int c = 0; c < 4; ++c)
            a[c] = rr[c] + ((4 * lane + c == Uv - 1) ? 0.0f : 1.0f);
        float r2 = l2add(l2add(a[0], a[1]), l2add(a[2], a[3]));
#pragma unroll
        for (int o = 32; o >= 1; o >>= 1) {
            float t = __shfl_xor(r2, o, 64);
            r2 = l2add(r2, t);
        }
        if (lane == 0) out[b] = r2 * LN2_F;
    }
}

extern "C" void kernel_launch(void* const* d_in, const int* in_sizes, int n_in,
                              void* d_out, int out_size, void* d_ws, size_t ws_size,
                              hipStream_t stream) {
    const float* lp = (const float*)d_in[0];
    const float* lens = (const float*)d_in[1];
    const int* phns = (const int*)d_in[2];
    const float* phn_lens = (const float*)d_in[3];
    float* out = (float*)d_out;
    (void)in_sizes; (void)n_in; (void)out_size;

    const size_t need = (size_t)Bc * Tc * Uc * sizeof(float); // 65.5 MB
    if (d_ws != nullptr && ws_size >= need) {
        float* el = (float*)d_ws;
        gather_kernel<<<dim3(Bc, GBLK), 128, 0, stream>>>(lp, lens, phns,
                                                          phn_lens, el);
        scan_kernel<<<Bc, 64, 0, stream>>>(el, phn_lens, out);
    } else {
        fused_hmm_kernel<<<Bc, 512, 0, stream>>>(lp, lens, phns, phn_lens, out);
    }
}

// Round 6
// 255.248 us; speedup vs baseline: 1.2612x; 1.0854x over previous
//
#include <hip/hip_runtime.h>
#include <math.h>

// Problem dims (fixed by setup_inputs)
constexpr int Bc = 64;
constexpr int Tc = 1000;
constexpr int Vc = 512;
constexpr int Uc = 256;
constexpr int CH = 50;        // t-rows per LDS chunk (scan)
constexpr int NCH = Tc / CH;  // 20 chunks
constexpr int PW = 7;         // fused fallback: producer waves
constexpr int SLOTS = 4;      // fused fallback: stage slots per producer wave

// gather kernel geometry
constexpr int GW = 2;            // waves per gather block
constexpr int GNR = 10;          // rows (slots) per wave, all in flight at once
constexpr int GROWS = GW * GNR;  // 20 rows per gather block
constexpr int GBLK = Tc / GROWS; // 50 gather blocks per batch elem

// scan fill: CH rows x 512 B (bf16) = 25.6 KB per chunk = 25 x 1KB dma16
constexpr int FPC = CH * Uc * 2 / 1024; // 25 dma16 per chunk

#define NEG_INF_F (-100000.0f)
#define LOG2E_F 1.44269504088896340736f
#define LN2_F 0.69314718055994530942f
#define DEAD_F (-1.0e9f)
#define EBIAS 30  // renorm target: lane max ~2^30

// s_waitcnt immediate: vmcnt(n), lgkm/exp ignored (gfx9 encoding:
// vmcnt[3:0]@[3:0], vmcnt[5:4]@[15:14], exp@[6:4]=7, lgkm@[11:8]=0xF)
#define WAITVM(n) __builtin_amdgcn_s_waitcnt(((n) & 15) | (((n) >> 4) << 14) | 0x0f70)

// raw v_exp_f32 (2^x) / v_log_f32 (log2 x)
__device__ __forceinline__ float fexp2(float x) {
#if __has_builtin(__builtin_amdgcn_exp2f)
    return __builtin_amdgcn_exp2f(x);
#else
    return __expf(x * LN2_F);
#endif
}
__device__ __forceinline__ float flog2(float x) {
#if __has_builtin(__builtin_amdgcn_logf)
    return __builtin_amdgcn_logf(x);
#else
    return __logf(x) * LOG2E_F;
#endif
}

// log2-domain logadd: log2(2^x + 2^y)
__device__ __forceinline__ float l2add(float x, float y) {
    float m = fmaxf(x, y);
    float p = fexp2(-fabsf(x - y));
    return m + flog2(1.0f + p);
}

// Whole-wave shift-up-by-1 via DPP wave_shr:1 (full-rate VALU op).
__device__ __forceinline__ float waveshr1(float x, float lane0val) {
    return __int_as_float(__builtin_amdgcn_update_dpp(
        __float_as_int(lane0val), __float_as_int(x),
        0x138 /* wave_shr:1 */, 0xF, 0xF, false));
}
__device__ __forceinline__ int waveshr1_i(int x) {
    return __builtin_amdgcn_update_dpp(x, x, 0x138, 0xF, 0xF, false);
}

// unpack 4 bf16 (packed uint2, memory order) -> float4
__device__ __forceinline__ float4 unbf(uint2 u) {
    float4 f;
    f.x = __uint_as_float(u.x << 16);
    f.y = __uint_as_float(u.x & 0xffff0000u);
    f.z = __uint_as_float(u.y << 16);
    f.w = __uint_as_float(u.y & 0xffff0000u);
    return f;
}
// pack two f32 -> two bf16 (RNE), b in high half
__device__ __forceinline__ unsigned int bfpack(float a, float b) {
    unsigned int xa = __float_as_uint(a), xb = __float_as_uint(b);
    xa = (xa + 0x7fffu + ((xa >> 16) & 1u)) >> 16;
    xb = (xb + 0x7fffu + ((xb >> 16) & 1u)) & 0xffff0000u;
    return xa | xb;
}

// LINEAR-domain HMM step, f32 mantissa with per-lane scale (value = rr*2^e).
__device__ __forceinline__ void hmm_step_f32(float rr[4], const float4 ev,
                                             float sc_d) {
    float nb0 = waveshr1(rr[3], 0.0f) * sc_d; // lane0: no predecessor -> 0
    float s0 = rr[0] + nb0;
    float s1 = rr[1] + rr[0];
    float s2 = rr[2] + rr[1];
    float s3 = rr[3] + rr[2];
    rr[0] = s0 * ev.x;
    rr[1] = s1 * ev.y;
    rr[2] = s2 * ev.z;
    rr[3] = s3 * ev.w;
}

// log2-domain HMM step (fallback kernel only)
__device__ __forceinline__ void hmm_step(float rr[4], const float4 ev) {
    float nb0 = waveshr1(rr[3], DEAD_F);
    float e[4] = {ev.x, ev.y, ev.z, ev.w};
    float nb[4] = {nb0, rr[0], rr[1], rr[2]};
#pragma unroll
    for (int c = 0; c < 4; ++c) {
        float x = rr[c], y = nb[c];
        float m = fmaxf(x, y);
        float p = fexp2(-fabsf(x - y));
        float me = m + e[c];
        rr[c] = me + flog2(1.0f + p);
    }
}

// async global->LDS DMA of 16 B/lane (1 KB per wave-instruction)
__device__ __forceinline__ void dma16(const void* gsrc, void* lds, int lane) {
    typedef const __attribute__((address_space(1))) unsigned int* gp_t;
    typedef __attribute__((address_space(3))) unsigned int* lp_t;
    __builtin_amdgcn_global_load_lds((gp_t)((const char*)gsrc + 16 * lane),
                                     (lp_t)lds, 16, 0, 0);
}

// ---------------------------------------------------------------------------
// Kernel A: gather + transform emissions to LINEAR bf16 EL[b][t][u].
// EL = 2^(lp*log2e + off); masked (u>=Uv or t>=Tv) -> 0. bf16 halves the
// intermediate traffic (rel-err 2^-9 on values spanning ~2^±9 -> ~0.1 nat).
// ---------------------------------------------------------------------------
__global__ __launch_bounds__(128, 2) void gather_kernel(
    const float* __restrict__ lp, const float* __restrict__ lens,
    const int* __restrict__ phns, const float* __restrict__ phn_lens,
    unsigned short* __restrict__ el) {
    __shared__ float stage[GW][GNR][Vc]; // 40 KB -> 4 blocks/CU
    const int b = blockIdx.x;
    const int t0 = blockIdx.y * GROWS;
    const int tid = threadIdx.x;
    const int wave = tid >> 6;
    const int lane = tid & 63;
    const int Tv = (int)rintf(lens[b] * (float)Tc);
    const int Uv = (int)rintf(phn_lens[b] * (float)Uc);
    const float* lpb = lp + (size_t)b * Tc * Vc;
    unsigned short* elb = el + ((size_t)b * Tc + t0) * Uc;

    int col[4];
    float off[4];
    bool pv[4];
    int4 cc = *(const int4*)(phns + (size_t)b * Uc + 4 * lane);
    int c4[4] = {cc.x, cc.y, cc.z, cc.w};
#pragma unroll
    for (int c = 0; c < 4; ++c) {
        int v = c4[c];
        v = v < 0 ? 0 : (v > Vc - 1 ? Vc - 1 : v);
        col[c] = v;
        int i = 4 * lane + c;
        pv[c] = (i < Uv);
        off[c] = (i == Uv - 1) ? 0.0f : -1.0f; // transition const (log2 units)
    }

    float* stw = &stage[wave][0][0];
    // issue ALL row loads (2 x dma16 per row, 20 vmem ops in flight)
#pragma unroll
    for (int j = 0; j < GNR; ++j) {
        int r = wave + j * GW;
        const float* gsrc = lpb + (size_t)(t0 + r) * Vc;
        float* st = stw + j * Vc;
        dma16(gsrc, st, lane);             // floats [0..255]
        dma16(gsrc + 256, st + 256, lane); // floats [256..511]
    }

    auto do_rows = [&](int j0) {
#pragma unroll
        for (int j = j0; j < j0 + GNR / 2; ++j) {
            int r = wave + j * GW;
            const bool tv = (t0 + r) < Tv;
            const float* st = stw + j * Vc;
            float ev[4];
#pragma unroll
            for (int c = 0; c < 4; ++c) {
                float e = st[col[c]]; // random-bank ds_read_b32 (cheap)
                ev[c] = (pv[c] && tv) ? fexp2(fmaf(e, LOG2E_F, off[c])) : 0.0f;
            }
            uint2 pk;
            pk.x = bfpack(ev[0], ev[1]);
            pk.y = bfpack(ev[2], ev[3]);
            *(uint2*)((char*)elb + (size_t)r * Uc * 2 + 8 * lane) = pk;
        }
    };

    WAITVM(10); // first 10 loads (rows j=0..4) landed
    do_rows(0);
    WAITVM(0); // rest landed
    do_rows(GNR / 2);
}

// ---------------------------------------------------------------------------
// Kernel B: sequential linear-domain scan over bf16 EL.
// SINGLE wave per block; 3 LDS buffers, 2 chunks of DMAs (50 loads) kept in
// flight at ALL times via counted vmcnt (never drains to 0 in-loop) -- the
// round-5 floor theory: per-chunk vmcnt(0) drains serialized the memory pipe.
// Renorm every 4 steps: per-lane exponent, exact pow2 scaling; zero lanes
// adopt left neighbor's exponent (frontier advances 1 lane / 4 steps).
// ---------------------------------------------------------------------------
__global__ __launch_bounds__(64, 1) void scan_kernel(
    const unsigned short* __restrict__ el, const float* __restrict__ phn_lens,
    float* __restrict__ out) {
    __shared__ unsigned short ebuf[3][CH][Uc]; // 75 KB triple buffer
    const int b = blockIdx.x;
    const int lane = threadIdx.x & 63;
    const int Uv = (int)rintf(phn_lens[b] * (float)Uc);
    const char* eb = (const char*)(el + (size_t)b * Tc * Uc);
    float rr[4];
    int e = 0;         // per-lane scale: true value = rr * 2^e
    float sc_d = 1.0f; // 2^(e_left - e), refreshed at each renorm

    auto fill = [&](int k) {
        const char* src = eb + (size_t)k * CH * Uc * 2;
        char* dst = (char*)&ebuf[k % 3][0][0];
#pragma unroll
        for (int i = 0; i < FPC; ++i)
            dma16(src + i * 1024, dst + i * 1024, lane);
    };

    auto renorm = [&]() {
        float m = fmaxf(fmaxf(rr[0], rr[1]), fmaxf(rr[2], rr[3]));
        int ep_old = waveshr1_i(e); // left neighbor's e (lane0: own)
        bool nz = (m > 0.0f);
        int ik = ((__float_as_int(m) >> 23) & 255) - 127 - EBIAS;
        ik = ik < -96 ? -96 : (ik > 96 ? 96 : ik);
        const float sc = __int_as_float((127 - ik) << 23); // exact 2^-ik
        rr[0] *= sc; rr[1] *= sc; rr[2] *= sc; rr[3] *= sc;
        e = nz ? (e + ik) : ep_old; // zero lanes adopt left's exponent
        int ep = waveshr1_i(e);
        int d = ep - e;
        int dc = d < -126 ? -126 : (d > 127 ? 127 : d);
        float sd = __int_as_float((127 + dc) << 23); // exact 2^d
        sc_d = (d < -126) ? 0.0f : sd; // mass < 2^-149 rel -> truly 0
    };

    auto consume = [&](int k) {
        const uint2* base = (const uint2*)&ebuf[k % 3][0][0] + lane; // 64/row
        int r = 0;
        if (k == 0) {
            float4 e0 = unbf(base[0]);
            float ea[4] = {e0.x, e0.y, e0.z, e0.w};
#pragma unroll
            for (int c = 0; c < 4; ++c)
                rr[c] = (4 * lane + c == 0) ? ea[c] : 0.0f; // pi * EL(0)
            r = 1;
        }
        uint2 q0, q1, q2, q3;
        if (r + 0 < CH) q0 = base[(r + 0) * 64];
        if (r + 1 < CH) q1 = base[(r + 1) * 64];
        if (r + 2 < CH) q2 = base[(r + 2) * 64];
        if (r + 3 < CH) q3 = base[(r + 3) * 64];
        while (r + 4 <= CH) {
            uint2 e0 = q0, e1 = q1, e2v = q2, e3 = q3;
            if (r + 4 < CH) q0 = base[(r + 4) * 64];
            if (r + 5 < CH) q1 = base[(r + 5) * 64];
            if (r + 6 < CH) q2 = base[(r + 6) * 64];
            if (r + 7 < CH) q3 = base[(r + 7) * 64];
            hmm_step_f32(rr, unbf(e0), sc_d);
            hmm_step_f32(rr, unbf(e1), sc_d);
            hmm_step_f32(rr, unbf(e2v), sc_d);
            hmm_step_f32(rr, unbf(e3), sc_d);
            renorm();
            r += 4;
        }
        bool tail = false;
        if (r + 0 < CH) { hmm_step_f32(rr, unbf(q0), sc_d); tail = true; }
        if (r + 1 < CH) { hmm_step_f32(rr, unbf(q1), sc_d); }
        if (r + 2 < CH) { hmm_step_f32(rr, unbf(q2), sc_d); }
        if (tail) renorm();
    };

    WAITVM(0); // quiesce any prologue vector loads before counting vmcnt
    fill(0);
    fill(1);
    fill(2);
    for (int k = 0; k < NCH; ++k) {
        // wait until fill(k) retired, keeping later fills in flight
        if (k + 2 < NCH) WAITVM(2 * FPC);      // 50: k+1,k+2 outstanding
        else if (k + 1 < NCH) WAITVM(FPC);     // 25: k+1 outstanding
        else WAITVM(0);
        consume(k);
        if (k + 3 < NCH) fill(k + 3); // after consume: (k+3)%3 == k%3 buffer
    }

    // undo per-state shift (x2 on non-last states), per-lane log2 + e,
    // then wave-wide logsumexp (log2 domain), back to nats.
    float a = 0.0f;
#pragma unroll
    for (int c = 0; c < 4; ++c)
        a += rr[c] * ((4 * lane + c == Uv - 1) ? 1.0f : 2.0f);
    float v = (a > 0.0f) ? (flog2(a) + (float)e) : -1.0e30f;
#pragma unroll
    for (int o = 32; o >= 1; o >>= 1) {
        float t = __shfl_xor(v, o, 64);
        v = l2add(v, t);
    }
    if (lane == 0) out[b] = v * LN2_F;
}

// ---------------------------------------------------------------------------
// Fallback: fused single-kernel log2-domain version (workspace too small).
// Passed verification (absmax 0.0) in earlier rounds.
// ---------------------------------------------------------------------------
__global__ __launch_bounds__(512, 1) void fused_hmm_kernel(
    const float* __restrict__ lp, const float* __restrict__ lens,
    const int* __restrict__ phns, const float* __restrict__ phn_lens,
    float* __restrict__ out) {
    __shared__ float ebuf[2][CH][Uc];      // 100 KB
    __shared__ float stage[PW][SLOTS][Vc]; // 56 KB
    const int b = blockIdx.x;
    const int tid = threadIdx.x;
    const int wave = tid >> 6;
    const int lane = tid & 63;
    const int Tv = (int)rintf(lens[b] * (float)Tc);
    const int Uv = (int)rintf(phn_lens[b] * (float)Uc);
    const float* lpb = lp + (size_t)b * Tc * Vc;

    int col[4];
    float off[4];
    bool pv[4];
    float rr[4];

    if (wave > 0) {
        int4 cc = *(const int4*)(phns + (size_t)b * Uc + 4 * lane);
        int c4[4] = {cc.x, cc.y, cc.z, cc.w};
#pragma unroll
        for (int c = 0; c < 4; ++c) {
            int v = c4[c];
            v = v < 0 ? 0 : (v > Vc - 1 ? Vc - 1 : v);
            col[c] = v;
            int i = 4 * lane + c;
            pv[c] = (i < Uv);
            off[c] = (i == Uv - 1) ? 0.0f : -1.0f;
        }
    }

    auto fill = [&](int k) {
        float* dst = &ebuf[k & 1][0][0];
        const int tb = k * CH;
        const int r0 = wave - 1;
        float* stw = &stage[wave - 1][0][0];
#pragma unroll
        for (int half = 0; half < 2; ++half) {
#pragma unroll
            for (int jj = 0; jj < SLOTS; ++jj) {
                int r = r0 + (half * SLOTS + jj) * PW;
                if (r < CH) {
                    const float* gsrc = lpb + (size_t)(tb + r) * Vc;
                    float* st = stw + jj * Vc;
                    dma16(gsrc, st, lane);
                    dma16(gsrc + 256, st + 256, lane);
                }
            }
            WAITVM(0);
#pragma unroll
            for (int jj = 0; jj < SLOTS; ++jj) {
                int r = r0 + (half * SLOTS + jj) * PW;
                if (r < CH) {
                    const bool tv = (tb + r) < Tv;
                    const float* st = stw + jj * Vc;
                    float ev[4];
#pragma unroll
                    for (int c = 0; c < 4; ++c) {
                        float e = st[col[c]];
                        ev[c] = (pv[c] && tv) ? fmaf(e, LOG2E_F, off[c])
                                              : (NEG_INF_F * LOG2E_F + off[c]);
                    }
                    *(float4*)(dst + r * Uc + 4 * lane) =
                        make_float4(ev[0], ev[1], ev[2], ev[3]);
                }
            }
        }
    };

    auto consume = [&](int k) {
        const float4* base = (const float4*)&ebuf[k & 1][0][0] + lane;
        int r = 0;
        if (k == 0) {
            float4 e0 = base[0];
            float ea[4] = {e0.x, e0.y, e0.z, e0.w};
#pragma unroll
            for (int c = 0; c < 4; ++c)
                rr[c] = ((4 * lane + c == 0) ? 0.0f : DEAD_F) + ea[c];
            r = 1;
        }
        float4 q0, q1, q2, q3;
        if (r + 0 < CH) q0 = base[(r + 0) * 64];
        if (r + 1 < CH) q1 = base[(r + 1) * 64];
        if (r + 2 < CH) q2 = base[(r + 2) * 64];
        if (r + 3 < CH) q3 = base[(r + 3) * 64];
        while (r + 4 <= CH) {
            float4 e0 = q0, e1 = q1, e2 = q2, e3 = q3;
            if (r + 4 < CH) q0 = base[(r + 4) * 64];
            if (r + 5 < CH) q1 = base[(r + 5) * 64];
            if (r + 6 < CH) q2 = base[(r + 6) * 64];
            if (r + 7 < CH) q3 = base[(r + 7) * 64];
            hmm_step(rr, e0);
            hmm_step(rr, e1);
            hmm_step(rr, e2);
            hmm_step(rr, e3);
            r += 4;
        }
        if (r + 0 < CH) hmm_step(rr, q0);
        if (r + 1 < CH) hmm_step(rr, q1);
        if (r + 2 < CH) hmm_step(rr, q2);
    };

    if (wave > 0) fill(0);
    __syncthreads();
    for (int k = 0; k < NCH; ++k) {
        if (wave > 0) {
            if (k + 1 < NCH) fill(k + 1);
        } else {
            consume(k);
        }
        __syncthreads();
    }

    if (wave == 0) {
        float a[4];
#pragma unroll
        for (int c = 0; c < 4; ++c)
            a[c] = rr[c] + ((4 * lane + c == Uv - 1) ? 0.0f : 1.0f);
        float r2 = l2add(l2add(a[0], a[1]), l2add(a[2], a[3]));
#pragma unroll
        for (int o = 32; o >= 1; o >>= 1) {
            float t = __shfl_xor(r2, o, 64);
            r2 = l2add(r2, t);
        }
        if (lane == 0) out[b] = r2 * LN2_F;
    }
}

extern "C" void kernel_launch(void* const* d_in, const int* in_sizes, int n_in,
                              void* d_out, int out_size, void* d_ws, size_t ws_size,
                              hipStream_t stream) {
    const float* lp = (const float*)d_in[0];
    const float* lens = (const float*)d_in[1];
    const int* phns = (const int*)d_in[2];
    const float* phn_lens = (const float*)d_in[3];
    float* out = (float*)d_out;
    (void)in_sizes; (void)n_in; (void)out_size;

    const size_t need = (size_t)Bc * Tc * Uc * 2; // 32.8 MB (bf16)
    if (d_ws != nullptr && ws_size >= need) {
        unsigned short* el = (unsigned short*)d_ws;
        gather_kernel<<<dim3(Bc, GBLK), 128, 0, stream>>>(lp, lens, phns,
                                                          phn_lens, el);
        scan_kernel<<<Bc, 64, 0, stream>>>(el, phn_lens, out);
    } else {
        fused_hmm_kernel<<<Bc, 512, 0, stream>>>(lp, lens, phns, phn_lens, out);
    }
}